// Round 2
// baseline (4305.685 us; speedup 1.0000x reference)
//
#include <hip/hip_runtime.h>
#include <hip/hip_fp16.h>
#include <math.h>

// Problem constants (Cross Swin block)
#define NB_B   8
#define NB_H   128
#define NB_W   128
#define NB_C   96
#define NB_WS  8
#define NB_SS  4
#define NB_NH  6
#define NB_HD  16
#define NB_N   64          // tokens per window
#define NB_NWIN 2048       // total windows (8 * 16 * 16)
#define NB_L   (NB_H*NB_W)
#define NB_MLPH 384
#define TOKENS_TOTAL (NB_B*NB_L)   // 131072

// LDS strides (padded to dodge bank conflicts)
#define XSTR 104   // fp16 row stride for 96-ch token rows
#define QSTR 17    // fp32 row stride for per-head [64 x 16] fragments
#define SSTR 66    // fp32 row stride for [64 x 64] score matrix

struct AttnParams {
  const float* x;
  const float* y;
  const float* g1[2];
  const float* b1[2];
  const float* qw[2];
  const float* qb[2];
  const float* kvw[2];
  const float* kvb[2];
  const float* pw[2];
  const float* pb[2];
  const float* rpb[2];
  float* att0;   // d_out first half: x + attn (fp32) [B*L, C]
  float* att1;   // d_out second half: y + attn
};

__global__ __launch_bounds__(256) void attn_kernel(AttnParams P){
  __shared__ __half xs[NB_N*XSTR];   // LN'd x window (fp16 storage)
  __shared__ __half ys[NB_N*XSTR];   // LN'd y window
  __shared__ float  qh[NB_N*QSTR];   // per-head q, then reused for per-head o
  __shared__ float  kh[NB_N*QSTR];
  __shared__ float  vh[NB_N*QSTR];
  __shared__ float  Sm[NB_N*SSTR];   // scores / probs
  __shared__ int    lab[NB_N];       // shift-mask region labels

  const int tid  = threadIdx.x;
  const int win  = blockIdx.x;
  const int b    = win >> 8;     // / 256
  const int widx = win & 255;
  const int wh   = widx >> 4;
  const int ww   = widx & 15;

  // Shift-mask labels for this window (rolled-frame coordinates)
  if (tid < NB_N){
    int r = tid >> 3, c = tid & 7;
    int i = wh*NB_WS + r, j = ww*NB_WS + c;
    int ri = (i < NB_H-NB_WS) ? 0 : ((i < NB_H-NB_SS) ? 1 : 2);
    int rj = (j < NB_W-NB_WS) ? 0 : ((j < NB_W-NB_SS) ? 1 : 2);
    lab[tid] = ri*3 + rj;
  }

  // Load x/y windows. Window token t sits at rolled coords (wh*8+r, ww*8+c);
  // the roll(-4,-4) means its source is orig ((i+4)&127, (j+4)&127).
  for (int f = tid; f < NB_N*24; f += 256){
    int t  = f / 24;
    int q4 = f - t*24;
    int r = t >> 3, cc = t & 7;
    int i = wh*NB_WS + r, j = ww*NB_WS + cc;
    int oi = (i + NB_SS) & (NB_H-1), oj = (j + NB_SS) & (NB_W-1);
    size_t base = ((size_t)((b*NB_H + oi)*NB_W + oj))*NB_C + q4*4;
    float4 ux = *(const float4*)(P.x + base);
    float4 uy = *(const float4*)(P.y + base);
    int o = t*XSTR + q4*4;
    xs[o+0] = __float2half(ux.x);
    xs[o+1] = __float2half(ux.y);
    xs[o+2] = __float2half(ux.z);
    xs[o+3] = __float2half(ux.w);
    ys[o+0] = __float2half(uy.x);
    ys[o+1] = __float2half(uy.y);
    ys[o+2] = __float2half(uy.z);
    ys[o+3] = __float2half(uy.w);
  }
  __syncthreads();

  // LayerNorm both windows in place. 4 threads per token row.
  {
    int t = tid >> 2, s = tid & 3;
    // x with (g1A, b1A)
    {
      float pm = 0.f;
      #pragma unroll
      for (int m=0;m<24;++m) pm += __half2float(xs[t*XSTR + s + 4*m]);
      pm += __shfl_xor(pm,1); pm += __shfl_xor(pm,2);
      float mu = pm*(1.f/96.f);
      float pv = 0.f;
      #pragma unroll
      for (int m=0;m<24;++m){ float d = __half2float(xs[t*XSTR+s+4*m])-mu; pv += d*d; }
      pv += __shfl_xor(pv,1); pv += __shfl_xor(pv,2);
      float rstd = rsqrtf(pv*(1.f/96.f) + 1e-5f);
      #pragma unroll
      for (int m=0;m<24;++m){
        int c = s + 4*m;
        float v = (__half2float(xs[t*XSTR+c])-mu)*rstd*P.g1[0][c] + P.b1[0][c];
        xs[t*XSTR+c] = __float2half(v);
      }
    }
    // y with (g1B, b1B)
    {
      float pm = 0.f;
      #pragma unroll
      for (int m=0;m<24;++m) pm += __half2float(ys[t*XSTR + s + 4*m]);
      pm += __shfl_xor(pm,1); pm += __shfl_xor(pm,2);
      float mu = pm*(1.f/96.f);
      float pv = 0.f;
      #pragma unroll
      for (int m=0;m<24;++m){ float d = __half2float(ys[t*XSTR+s+4*m])-mu; pv += d*d; }
      pv += __shfl_xor(pv,1); pv += __shfl_xor(pv,2);
      float rstd = rsqrtf(pv*(1.f/96.f) + 1e-5f);
      #pragma unroll
      for (int m=0;m<24;++m){
        int c = s + 4*m;
        float v = (__half2float(ys[t*XSTR+c])-mu)*rstd*P.g1[1][c] + P.b1[1][c];
        ys[t*XSTR+c] = __float2half(v);
      }
    }
  }
  __syncthreads();

  // Two cross-attention streams: s2=0 (A: q from x, kv from y, out->x side),
  // s2=1 (B: q from y, kv from x, out->y side).
  for (int s2 = 0; s2 < 2; ++s2){
    const __half* qsrc = s2 ? ys : xs;
    const __half* ksrc = s2 ? xs : ys;
    const float* qw  = P.qw[s2];
    const float* qb  = P.qb[s2];
    const float* kvw = P.kvw[s2];
    const float* kvb = P.kvb[s2];
    const float* pw  = P.pw[s2];
    const float* pb  = P.pb[s2];
    const float* rpb = P.rpb[s2];

    float accO[24];
    #pragma unroll
    for (int m=0;m<24;++m) accO[m] = 0.f;

    for (int h = 0; h < NB_NH; ++h){
      // Per-head q/k/v projection: columns h*16 .. h*16+15
      for (int f = tid; f < NB_N*NB_HD; f += 256){
        int d = f & 15, t = f >> 4;
        int c = h*16 + d;
        float aq = 0.f, ak = 0.f, av = 0.f;
        for (int k = 0; k < 96; ++k){
          float xv = __half2float(qsrc[t*XSTR+k]);
          float yv = __half2float(ksrc[t*XSTR+k]);
          aq += xv * qw [k*96  + c];
          ak += yv * kvw[k*192 + c];
          av += yv * kvw[k*192 + 96 + c];
        }
        qh[t*QSTR+d] = (aq + qb[c]) * 0.25f;   // scale = hd^-0.5
        kh[t*QSTR+d] = ak + kvb[c];
        vh[t*QSTR+d] = av + kvb[96+c];
      }
      __syncthreads();

      // Scores + rel-pos bias + shift mask
      for (int f = tid; f < NB_N*NB_N; f += 256){
        int j = f & 63, i = f >> 6;
        float a = 0.f;
        #pragma unroll
        for (int d=0; d<16; ++d) a += qh[i*QSTR+d]*kh[j*QSTR+d];
        int iq = i>>3, jq = i&7, ik = j>>3, jk = j&7;
        int rp = (iq-ik+7)*15 + (jq-jk+7);
        a += rpb[rp*NB_NH + h];
        a += (lab[i]==lab[j]) ? 0.f : -100.f;
        Sm[i*SSTR + j] = a;
      }
      __syncthreads();

      // Softmax per row (4 threads/row)
      {
        int t = tid >> 2, s = tid & 3;
        float mx = -1e30f;
        #pragma unroll
        for (int m=0;m<16;++m) mx = fmaxf(mx, Sm[t*SSTR + s + 4*m]);
        mx = fmaxf(mx, __shfl_xor(mx,1)); mx = fmaxf(mx, __shfl_xor(mx,2));
        float ev[16]; float sm = 0.f;
        #pragma unroll
        for (int m=0;m<16;++m){ ev[m] = __expf(Sm[t*SSTR+s+4*m]-mx); sm += ev[m]; }
        sm += __shfl_xor(sm,1); sm += __shfl_xor(sm,2);
        float inv = 1.f/sm;
        #pragma unroll
        for (int m=0;m<16;++m) Sm[t*SSTR+s+4*m] = ev[m]*inv;
      }
      __syncthreads();

      // o_h = P @ v_h  -> overwrite qh (its cols for head h are dead now)
      for (int f = tid; f < NB_N*NB_HD; f += 256){
        int d = f & 15, i = f >> 4;
        float a = 0.f;
        for (int j=0;j<64;++j) a += Sm[i*SSTR+j]*vh[j*QSTR+d];
        qh[i*QSTR+d] = a;
      }
      __syncthreads();

      // Output projection, head-sliced: out[t][c] += sum_k o_h[t][k] * pw[h*16+k][c]
      #pragma unroll
      for (int m=0;m<24;++m){
        int f = tid + 256*m;
        int c = f % 96, t = f / 96;
        float a = accO[m];
        #pragma unroll
        for (int k=0;k<16;++k) a += qh[t*QSTR+k]*pw[(h*16+k)*96 + c];
        accO[m] = a;
      }
      __syncthreads();
    }

    // Epilogue: + proj bias + residual (orig, un-rolled coords), store fp32
    const float* resid = s2 ? P.y : P.x;
    float* outp = s2 ? P.att1 : P.att0;
    #pragma unroll
    for (int m=0;m<24;++m){
      int f = tid + 256*m;
      int c = f % 96, t = f / 96;
      int r = t>>3, cc = t&7;
      int i = wh*NB_WS + r, j = ww*NB_WS + cc;
      int oi = (i + NB_SS) & (NB_H-1), oj = (j + NB_SS) & (NB_W-1);
      size_t g = ((size_t)((b*NB_H + oi)*NB_W + oj))*NB_C + c;
      outp[g] = accO[m] + pb[c] + resid[g];
    }
    __syncthreads();
  }
}

struct MlpParams {
  const float* src0;   // d_out first half: x + attn (fp32)
  const float* src1;   // d_out second half
  const float* g2[2];
  const float* bt2[2];
  const float* w1[2];
  const float* bb1[2];
  const float* w2[2];
  const float* bb2[2];
  float* out;          // d_out (in-place update)
};

#define MLP_TT 16   // tokens per block

__global__ __launch_bounds__(256) void mlp_kernel(MlpParams P){
  __shared__ float xt[MLP_TT*100];    // LN'd tokens
  __shared__ float hh[MLP_TT*388];    // fc1 activations

  const int tid  = threadIdx.x;
  const int s2   = blockIdx.x >> 13;        // 8192 blocks per stream
  const int blk  = blockIdx.x & 8191;
  const int tok0 = blk * MLP_TT;
  const float* src = s2 ? P.src1 : P.src0;

  // Load raw tokens
  for (int f = tid; f < MLP_TT*96; f += 256){
    int t = f / 96, c = f - t*96;
    xt[t*100+c] = src[(size_t)(tok0+t)*96 + c];
  }
  __syncthreads();

  // LayerNorm in place (16 threads per row)
  {
    int t = tid >> 4, s = tid & 15;
    float pm = 0.f;
    #pragma unroll
    for (int m=0;m<6;++m) pm += xt[t*100 + s + 16*m];
    pm += __shfl_xor(pm,1); pm += __shfl_xor(pm,2);
    pm += __shfl_xor(pm,4); pm += __shfl_xor(pm,8);
    float mu = pm*(1.f/96.f);
    float pv = 0.f;
    #pragma unroll
    for (int m=0;m<6;++m){ float d = xt[t*100+s+16*m]-mu; pv += d*d; }
    pv += __shfl_xor(pv,1); pv += __shfl_xor(pv,2);
    pv += __shfl_xor(pv,4); pv += __shfl_xor(pv,8);
    float rstd = rsqrtf(pv*(1.f/96.f) + 1e-5f);
    const float* g = P.g2[s2];
    const float* bb = P.bt2[s2];
    #pragma unroll
    for (int m=0;m<6;++m){
      int c = s+16*m;
      xt[t*100+c] = (xt[t*100+c]-mu)*rstd*g[c] + bb[c];
    }
  }
  __syncthreads();

  // fc1 + exact GELU
  {
    const float* w1 = P.w1[s2];
    const float* b1 = P.bb1[s2];
    for (int f = tid; f < MLP_TT*NB_MLPH; f += 256){
      int t = f / NB_MLPH, j = f - t*NB_MLPH;
      float a = 0.f;
      for (int k=0;k<96;++k) a += xt[t*100+k]*w1[k*NB_MLPH+j];
      a += b1[j];
      hh[t*388+j] = 0.5f*a*(1.f + erff(a*0.70710678118654752f));
    }
  }
  __syncthreads();

  // fc2 + residual -> fp32 out (in place; each gidx touched by exactly one thread)
  {
    const float* w2 = P.w2[s2];
    const float* b2v = P.bb2[s2];
    float* outp = P.out + (size_t)s2*TOKENS_TOTAL*96;
    for (int f = tid; f < MLP_TT*96; f += 256){
      int t = f / 96, c = f - t*96;
      float a = 0.f;
      for (int j=0;j<NB_MLPH;++j) a += hh[t*388+j]*w2[j*96+c];
      size_t gidx = (size_t)(tok0+t)*96 + c;
      a += b2v[c] + src[gidx];
      outp[gidx] = a;
    }
  }
}

extern "C" void kernel_launch(void* const* d_in, const int* in_sizes, int n_in,
                              void* d_out, int out_size, void* d_ws, size_t ws_size,
                              hipStream_t stream){
  // Input order: x, y, h, w, then per stream (A then B):
  // g1, b1, qw, qb, kvw, kvb, pw, pb, rpb, g2, b2, f1w, f1b, f2w, f2b
  float* xatt = (float*)d_out;                         // [B*L, C] fp32
  float* yatt = xatt + (size_t)TOKENS_TOTAL*NB_C;      // second output half

  AttnParams ap;
  ap.x = (const float*)d_in[0];
  ap.y = (const float*)d_in[1];
  MlpParams mp;
  mp.src0 = xatt; mp.src1 = yatt;
  mp.out = (float*)d_out;

  for (int s=0;s<2;++s){
    int o = 4 + 15*s;
    ap.g1[s]  = (const float*)d_in[o+0];
    ap.b1[s]  = (const float*)d_in[o+1];
    ap.qw[s]  = (const float*)d_in[o+2];
    ap.qb[s]  = (const float*)d_in[o+3];
    ap.kvw[s] = (const float*)d_in[o+4];
    ap.kvb[s] = (const float*)d_in[o+5];
    ap.pw[s]  = (const float*)d_in[o+6];
    ap.pb[s]  = (const float*)d_in[o+7];
    ap.rpb[s] = (const float*)d_in[o+8];
    mp.g2[s]  = (const float*)d_in[o+9];
    mp.bt2[s] = (const float*)d_in[o+10];
    mp.w1[s]  = (const float*)d_in[o+11];
    mp.bb1[s] = (const float*)d_in[o+12];
    mp.w2[s]  = (const float*)d_in[o+13];
    mp.bb2[s] = (const float*)d_in[o+14];
  }
  ap.att0 = xatt; ap.att1 = yatt;

  attn_kernel<<<NB_NWIN, 256, 0, stream>>>(ap);
  mlp_kernel<<<2*(TOKENS_TOTAL/MLP_TT), 256, 0, stream>>>(mp);
}

// Round 3
// 1975.235 us; speedup vs baseline: 2.1798x; 2.1798x over previous
//
#include <hip/hip_runtime.h>
#include <hip/hip_fp16.h>
#include <math.h>

// Problem constants (Cross Swin block)
#define NB_B   8
#define NB_H   128
#define NB_W   128
#define NB_C   96
#define NB_WS  8
#define NB_SS  4
#define NB_NH  6
#define NB_HD  16
#define NB_N   64          // tokens per window
#define NB_NWIN 2048       // total windows (8 * 16 * 16)
#define NB_L   (NB_H*NB_W)
#define NB_MLPH 384
#define TOKENS_TOTAL (NB_B*NB_L)   // 131072

// LDS strides (padded to dodge bank conflicts)
#define XSTR 104   // fp16 row stride for 96-ch token rows (attn kernel)
#define QSTR 17    // fp32 row stride for per-head [64 x 16] fragments
#define SSTR 66    // fp32 row stride for [64 x 64] score matrix

typedef _Float16 half8 __attribute__((ext_vector_type(8)));
typedef float    f32x4 __attribute__((ext_vector_type(4)));

// ============================ ATTENTION (unchanged from passing round) =====

struct AttnParams {
  const float* x;
  const float* y;
  const float* g1[2];
  const float* b1[2];
  const float* qw[2];
  const float* qb[2];
  const float* kvw[2];
  const float* kvb[2];
  const float* pw[2];
  const float* pb[2];
  const float* rpb[2];
  float* att0;   // d_out first half: x + attn (fp32) [B*L, C]
  float* att1;   // d_out second half: y + attn
};

__global__ __launch_bounds__(256) void attn_kernel(AttnParams P){
  __shared__ __half xs[NB_N*XSTR];   // LN'd x window (fp16 storage)
  __shared__ __half ys[NB_N*XSTR];   // LN'd y window
  __shared__ float  qh[NB_N*QSTR];   // per-head q, then reused for per-head o
  __shared__ float  kh[NB_N*QSTR];
  __shared__ float  vh[NB_N*QSTR];
  __shared__ float  Sm[NB_N*SSTR];   // scores / probs
  __shared__ int    lab[NB_N];       // shift-mask region labels

  const int tid  = threadIdx.x;
  const int win  = blockIdx.x;
  const int b    = win >> 8;     // / 256
  const int widx = win & 255;
  const int wh   = widx >> 4;
  const int ww   = widx & 15;

  if (tid < NB_N){
    int r = tid >> 3, c = tid & 7;
    int i = wh*NB_WS + r, j = ww*NB_WS + c;
    int ri = (i < NB_H-NB_WS) ? 0 : ((i < NB_H-NB_SS) ? 1 : 2);
    int rj = (j < NB_W-NB_WS) ? 0 : ((j < NB_W-NB_SS) ? 1 : 2);
    lab[tid] = ri*3 + rj;
  }

  for (int f = tid; f < NB_N*24; f += 256){
    int t  = f / 24;
    int q4 = f - t*24;
    int r = t >> 3, cc = t & 7;
    int i = wh*NB_WS + r, j = ww*NB_WS + cc;
    int oi = (i + NB_SS) & (NB_H-1), oj = (j + NB_SS) & (NB_W-1);
    size_t base = ((size_t)((b*NB_H + oi)*NB_W + oj))*NB_C + q4*4;
    float4 ux = *(const float4*)(P.x + base);
    float4 uy = *(const float4*)(P.y + base);
    int o = t*XSTR + q4*4;
    xs[o+0] = __float2half(ux.x);
    xs[o+1] = __float2half(ux.y);
    xs[o+2] = __float2half(ux.z);
    xs[o+3] = __float2half(ux.w);
    ys[o+0] = __float2half(uy.x);
    ys[o+1] = __float2half(uy.y);
    ys[o+2] = __float2half(uy.z);
    ys[o+3] = __float2half(uy.w);
  }
  __syncthreads();

  {
    int t = tid >> 2, s = tid & 3;
    {
      float pm = 0.f;
      #pragma unroll
      for (int m=0;m<24;++m) pm += __half2float(xs[t*XSTR + s + 4*m]);
      pm += __shfl_xor(pm,1); pm += __shfl_xor(pm,2);
      float mu = pm*(1.f/96.f);
      float pv = 0.f;
      #pragma unroll
      for (int m=0;m<24;++m){ float d = __half2float(xs[t*XSTR+s+4*m])-mu; pv += d*d; }
      pv += __shfl_xor(pv,1); pv += __shfl_xor(pv,2);
      float rstd = rsqrtf(pv*(1.f/96.f) + 1e-5f);
      #pragma unroll
      for (int m=0;m<24;++m){
        int c = s + 4*m;
        float v = (__half2float(xs[t*XSTR+c])-mu)*rstd*P.g1[0][c] + P.b1[0][c];
        xs[t*XSTR+c] = __float2half(v);
      }
    }
    {
      float pm = 0.f;
      #pragma unroll
      for (int m=0;m<24;++m) pm += __half2float(ys[t*XSTR + s + 4*m]);
      pm += __shfl_xor(pm,1); pm += __shfl_xor(pm,2);
      float mu = pm*(1.f/96.f);
      float pv = 0.f;
      #pragma unroll
      for (int m=0;m<24;++m){ float d = __half2float(ys[t*XSTR+s+4*m])-mu; pv += d*d; }
      pv += __shfl_xor(pv,1); pv += __shfl_xor(pv,2);
      float rstd = rsqrtf(pv*(1.f/96.f) + 1e-5f);
      #pragma unroll
      for (int m=0;m<24;++m){
        int c = s + 4*m;
        float v = (__half2float(ys[t*XSTR+c])-mu)*rstd*P.g1[1][c] + P.b1[1][c];
        ys[t*XSTR+c] = __float2half(v);
      }
    }
  }
  __syncthreads();

  for (int s2 = 0; s2 < 2; ++s2){
    const __half* qsrc = s2 ? ys : xs;
    const __half* ksrc = s2 ? xs : ys;
    const float* qw  = P.qw[s2];
    const float* qb  = P.qb[s2];
    const float* kvw = P.kvw[s2];
    const float* kvb = P.kvb[s2];
    const float* pw  = P.pw[s2];
    const float* pb  = P.pb[s2];
    const float* rpb = P.rpb[s2];

    float accO[24];
    #pragma unroll
    for (int m=0;m<24;++m) accO[m] = 0.f;

    for (int h = 0; h < NB_NH; ++h){
      for (int f = tid; f < NB_N*NB_HD; f += 256){
        int d = f & 15, t = f >> 4;
        int c = h*16 + d;
        float aq = 0.f, ak = 0.f, av = 0.f;
        for (int k = 0; k < 96; ++k){
          float xv = __half2float(qsrc[t*XSTR+k]);
          float yv = __half2float(ksrc[t*XSTR+k]);
          aq += xv * qw [k*96  + c];
          ak += yv * kvw[k*192 + c];
          av += yv * kvw[k*192 + 96 + c];
        }
        qh[t*QSTR+d] = (aq + qb[c]) * 0.25f;
        kh[t*QSTR+d] = ak + kvb[c];
        vh[t*QSTR+d] = av + kvb[96+c];
      }
      __syncthreads();

      for (int f = tid; f < NB_N*NB_N; f += 256){
        int j = f & 63, i = f >> 6;
        float a = 0.f;
        #pragma unroll
        for (int d=0; d<16; ++d) a += qh[i*QSTR+d]*kh[j*QSTR+d];
        int iq = i>>3, jq = i&7, ik = j>>3, jk = j&7;
        int rp = (iq-ik+7)*15 + (jq-jk+7);
        a += rpb[rp*NB_NH + h];
        a += (lab[i]==lab[j]) ? 0.f : -100.f;
        Sm[i*SSTR + j] = a;
      }
      __syncthreads();

      {
        int t = tid >> 2, s = tid & 3;
        float mx = -1e30f;
        #pragma unroll
        for (int m=0;m<16;++m) mx = fmaxf(mx, Sm[t*SSTR + s + 4*m]);
        mx = fmaxf(mx, __shfl_xor(mx,1)); mx = fmaxf(mx, __shfl_xor(mx,2));
        float ev[16]; float sm = 0.f;
        #pragma unroll
        for (int m=0;m<16;++m){ ev[m] = __expf(Sm[t*SSTR+s+4*m]-mx); sm += ev[m]; }
        sm += __shfl_xor(sm,1); sm += __shfl_xor(sm,2);
        float inv = 1.f/sm;
        #pragma unroll
        for (int m=0;m<16;++m) Sm[t*SSTR+s+4*m] = ev[m]*inv;
      }
      __syncthreads();

      for (int f = tid; f < NB_N*NB_HD; f += 256){
        int d = f & 15, i = f >> 4;
        float a = 0.f;
        for (int j=0;j<64;++j) a += Sm[i*SSTR+j]*vh[j*QSTR+d];
        qh[i*QSTR+d] = a;
      }
      __syncthreads();

      #pragma unroll
      for (int m=0;m<24;++m){
        int f = tid + 256*m;
        int c = f % 96, t = f / 96;
        float a = accO[m];
        #pragma unroll
        for (int k=0;k<16;++k) a += qh[t*QSTR+k]*pw[(h*16+k)*96 + c];
        accO[m] = a;
      }
      __syncthreads();
    }

    const float* resid = s2 ? P.y : P.x;
    float* outp = s2 ? P.att1 : P.att0;
    #pragma unroll
    for (int m=0;m<24;++m){
      int f = tid + 256*m;
      int c = f % 96, t = f / 96;
      int r = t>>3, cc = t&7;
      int i = wh*NB_WS + r, j = ww*NB_WS + cc;
      int oi = (i + NB_SS) & (NB_H-1), oj = (j + NB_SS) & (NB_W-1);
      size_t g = ((size_t)((b*NB_H + oi)*NB_W + oj))*NB_C + c;
      outp[g] = accO[m] + pb[c] + resid[g];
    }
    __syncthreads();
  }
}

// ============================ MLP: prep (pack weights to f16 fragments) ====
// Packed layout per stream in d_ws (all _Float16):
//   W1pack: 36864 = 24 ntiles x 3 kblocks x 64 lanes x 8
//   W2pack: 36864 =  6 ntiles x 12 kblocks x 64 lanes x 8
// B fragment mapping (mfma_f32_16x16x32): n = lane&15, k = (lane>>4)*8 + j.

struct PrepParams {
  const float* w1[2];
  const float* w2[2];
  _Float16* dst;     // [2][73728]
};

__global__ __launch_bounds__(256) void prep_kernel(PrepParams P){
  int idx = blockIdx.x*256 + threadIdx.x;      // [0, 147456)
  int s2 = idx / 73728;
  int r  = idx - s2*73728;
  int which = r / 36864;
  int p  = r - which*36864;
  int j    = p & 7;
  int lane = (p >> 3) & 63;
  int frag = p >> 9;
  int k, n;
  float v;
  if (which == 0){
    int kb = frag % 3, nt = frag / 3;
    k = kb*32 + (lane>>4)*8 + j;
    n = nt*16 + (lane & 15);
    v = P.w1[s2][k*NB_MLPH + n];
  } else {
    int kb = frag % 12, nt = frag / 12;
    k = kb*32 + (lane>>4)*8 + j;
    n = nt*16 + (lane & 15);
    v = P.w2[s2][k*NB_C + n];
  }
  P.dst[(size_t)s2*73728 + which*36864 + p] = (_Float16)v;
}

// ============================ MLP: MFMA kernel =============================

#define MT 64      // tokens per block
#define XS2 104    // f16 LDS stride for X (13312 B)
#define HS2 392    // f16 LDS stride for H (50176 B)

struct Mlp2Params {
  const float* g2[2];
  const float* bt2[2];
  const float* bb1[2];
  const float* bb2[2];
  const _Float16* wpack;  // [2][73728]
  float* out;             // d_out base (in-place update), stream offset s2*T*96
};

__global__ __launch_bounds__(256,2) void mlp_mfma_kernel(Mlp2Params P){
  __shared__ _Float16 Xs[MT*XS2];
  __shared__ _Float16 Hb[MT*HS2];
  float* Ftmp = (float*)Hb;          // 64x100 fp32 alias, dead before Hb use

  const int tid  = threadIdx.x;
  const int wave = tid >> 6;
  const int lane = tid & 63;
  const int mrow = lane & 15;
  const int quad = lane >> 4;
  const int s2   = blockIdx.x >> 11;       // 2048 blocks per stream
  const int blk  = blockIdx.x & 2047;
  const int tok0 = blk * MT;

  float* outp = P.out + (size_t)s2*TOKENS_TOTAL*NB_C;
  const float* src = outp;                 // in-place: read attn-out, write final

  // ---- load 64 tokens (fp32) into Ftmp
  for (int f = tid; f < MT*24; f += 256){
    int t = f / 24, q = f - t*24;
    float4 v = *(const float4*)(src + (size_t)(tok0+t)*NB_C + q*4);
    Ftmp[t*100+q*4+0] = v.x;
    Ftmp[t*100+q*4+1] = v.y;
    Ftmp[t*100+q*4+2] = v.z;
    Ftmp[t*100+q*4+3] = v.w;
  }
  __syncthreads();

  // ---- LayerNorm (fp32) -> Xs (f16). 4 threads per row.
  {
    int t = tid >> 2, s = tid & 3;
    float pm = 0.f;
    #pragma unroll
    for (int m=0;m<24;++m) pm += Ftmp[t*100 + s + 4*m];
    pm += __shfl_xor(pm,1); pm += __shfl_xor(pm,2);
    float mu = pm*(1.f/96.f);
    float pv = 0.f;
    #pragma unroll
    for (int m=0;m<24;++m){ float d = Ftmp[t*100+s+4*m]-mu; pv += d*d; }
    pv += __shfl_xor(pv,1); pv += __shfl_xor(pv,2);
    float rstd = rsqrtf(pv*(1.f/96.f) + 1e-5f);
    const float* g  = P.g2[s2];
    const float* bb = P.bt2[s2];
    #pragma unroll
    for (int m=0;m<24;++m){
      int c = s + 4*m;
      Xs[t*XS2+c] = (_Float16)((Ftmp[t*100+c]-mu)*rstd*g[c] + bb[c]);
    }
  }
  __syncthreads();

  // ---- GEMM1: H[64x384] = X[64x96] @ W1[96x384], +bias, GELU -> Hb (f16)
  // wave w covers output cols [w*96, w*96+96) (6 ntiles), all 4 rowgroups.
  const _Float16* w1p = P.wpack + (size_t)s2*73728;
  const _Float16* w2p = w1p + 36864;
  const float* b1 = P.bb1[s2];

  half8 Bf[18];
  #pragma unroll
  for (int nt=0; nt<6; ++nt)
    #pragma unroll
    for (int kb=0; kb<3; ++kb)
      Bf[nt*3+kb] = *(const half8*)(w1p + ((((wave*6+nt)*3 + kb)*64 + lane) << 3));

  #pragma unroll
  for (int rg=0; rg<4; ++rg){
    half8 Af[3];
    #pragma unroll
    for (int kb=0; kb<3; ++kb)
      Af[kb] = *(const half8*)(&Xs[(rg*16+mrow)*XS2 + kb*32 + quad*8]);
    #pragma unroll
    for (int nt=0; nt<6; ++nt){
      f32x4 acc = {0.f,0.f,0.f,0.f};
      #pragma unroll
      for (int kb=0; kb<3; ++kb)
        acc = __builtin_amdgcn_mfma_f32_16x16x32_f16(Af[kb], Bf[nt*3+kb], acc, 0, 0, 0);
      int gcol = wave*96 + nt*16 + mrow;    // C/D: col = lane&15
      float bias = b1[gcol];
      #pragma unroll
      for (int r=0;r<4;++r){                // C/D: row = quad*4 + r
        float a = acc[r] + bias;
        a = 0.5f*a*(1.f + erff(a*0.70710678118654752f));
        Hb[(rg*16 + quad*4 + r)*HS2 + gcol] = (_Float16)a;
      }
    }
  }
  __syncthreads();

  // ---- GEMM2: out[64x96] = H[64x384] @ W2[384x96] + bias + residual
  // wave w handles its own 16 rows (rowgroup w), all 6 ntiles.
  const float* b2 = P.bb2[s2];
  half8 Ag[12];
  #pragma unroll
  for (int kb=0; kb<12; ++kb)
    Ag[kb] = *(const half8*)(&Hb[(wave*16+mrow)*HS2 + kb*32 + quad*8]);

  #pragma unroll
  for (int nt=0; nt<6; ++nt){
    f32x4 acc = {0.f,0.f,0.f,0.f};
    #pragma unroll
    for (int kb=0; kb<12; ++kb){
      half8 b = *(const half8*)(w2p + (((nt*12+kb)*64 + lane) << 3));
      acc = __builtin_amdgcn_mfma_f32_16x16x32_f16(Ag[kb], b, acc, 0, 0, 0);
    }
    int gcol = nt*16 + mrow;
    float bias = b2[gcol];
    #pragma unroll
    for (int r=0;r<4;++r){
      int row = wave*16 + quad*4 + r;
      size_t g = (size_t)(tok0+row)*NB_C + gcol;
      outp[g] = acc[r] + bias + src[g];
    }
  }
}

// ============================ MLP fallback (scalar, if ws too small) =======

struct MlpParams {
  const float* src0;
  const float* src1;
  const float* g2[2];
  const float* bt2[2];
  const float* w1[2];
  const float* bb1[2];
  const float* w2[2];
  const float* bb2[2];
  float* out;
};

#define MLP_TT 16

__global__ __launch_bounds__(256) void mlp_kernel(MlpParams P){
  __shared__ float xt[MLP_TT*100];
  __shared__ float hh[MLP_TT*388];

  const int tid  = threadIdx.x;
  const int s2   = blockIdx.x >> 13;
  const int blk  = blockIdx.x & 8191;
  const int tok0 = blk * MLP_TT;
  const float* src = s2 ? P.src1 : P.src0;

  for (int f = tid; f < MLP_TT*96; f += 256){
    int t = f / 96, c = f - t*96;
    xt[t*100+c] = src[(size_t)(tok0+t)*96 + c];
  }
  __syncthreads();
  {
    int t = tid >> 4, s = tid & 15;
    float pm = 0.f;
    #pragma unroll
    for (int m=0;m<6;++m) pm += xt[t*100 + s + 16*m];
    pm += __shfl_xor(pm,1); pm += __shfl_xor(pm,2);
    pm += __shfl_xor(pm,4); pm += __shfl_xor(pm,8);
    float mu = pm*(1.f/96.f);
    float pv = 0.f;
    #pragma unroll
    for (int m=0;m<6;++m){ float d = xt[t*100+s+16*m]-mu; pv += d*d; }
    pv += __shfl_xor(pv,1); pv += __shfl_xor(pv,2);
    pv += __shfl_xor(pv,4); pv += __shfl_xor(pv,8);
    float rstd = rsqrtf(pv*(1.f/96.f) + 1e-5f);
    const float* g = P.g2[s2];
    const float* bb = P.bt2[s2];
    #pragma unroll
    for (int m=0;m<6;++m){
      int c = s+16*m;
      xt[t*100+c] = (xt[t*100+c]-mu)*rstd*g[c] + bb[c];
    }
  }
  __syncthreads();
  {
    const float* w1 = P.w1[s2];
    const float* b1 = P.bb1[s2];
    for (int f = tid; f < MLP_TT*NB_MLPH; f += 256){
      int t = f / NB_MLPH, j = f - t*NB_MLPH;
      float a = 0.f;
      for (int k=0;k<96;++k) a += xt[t*100+k]*w1[k*NB_MLPH+j];
      a += b1[j];
      hh[t*388+j] = 0.5f*a*(1.f + erff(a*0.70710678118654752f));
    }
  }
  __syncthreads();
  {
    const float* w2 = P.w2[s2];
    const float* b2v = P.bb2[s2];
    float* outp = P.out + (size_t)s2*TOKENS_TOTAL*96;
    for (int f = tid; f < MLP_TT*96; f += 256){
      int t = f / 96, c = f - t*96;
      float a = 0.f;
      for (int j=0;j<NB_MLPH;++j) a += hh[t*388+j]*w2[j*96+c];
      size_t gidx = (size_t)(tok0+t)*96 + c;
      a += b2v[c] + src[gidx];
      outp[gidx] = a;
    }
  }
}

// ============================ launcher =====================================

extern "C" void kernel_launch(void* const* d_in, const int* in_sizes, int n_in,
                              void* d_out, int out_size, void* d_ws, size_t ws_size,
                              hipStream_t stream){
  float* xatt = (float*)d_out;
  float* yatt = xatt + (size_t)TOKENS_TOTAL*NB_C;

  AttnParams ap;
  ap.x = (const float*)d_in[0];
  ap.y = (const float*)d_in[1];

  PrepParams pp;
  Mlp2Params m2;
  MlpParams mp;
  mp.src0 = xatt; mp.src1 = yatt;
  mp.out = (float*)d_out;
  m2.out = (float*)d_out;
  m2.wpack = (const _Float16*)d_ws;
  pp.dst = (_Float16*)d_ws;

  for (int s=0;s<2;++s){
    int o = 4 + 15*s;
    ap.g1[s]  = (const float*)d_in[o+0];
    ap.b1[s]  = (const float*)d_in[o+1];
    ap.qw[s]  = (const float*)d_in[o+2];
    ap.qb[s]  = (const float*)d_in[o+3];
    ap.kvw[s] = (const float*)d_in[o+4];
    ap.kvb[s] = (const float*)d_in[o+5];
    ap.pw[s]  = (const float*)d_in[o+6];
    ap.pb[s]  = (const float*)d_in[o+7];
    ap.rpb[s] = (const float*)d_in[o+8];
    m2.g2[s]  = (const float*)d_in[o+9];
    m2.bt2[s] = (const float*)d_in[o+10];
    m2.bb1[s] = (const float*)d_in[o+12];
    m2.bb2[s] = (const float*)d_in[o+14];
    pp.w1[s]  = (const float*)d_in[o+11];
    pp.w2[s]  = (const float*)d_in[o+13];
    mp.g2[s]  = (const float*)d_in[o+9];
    mp.bt2[s] = (const float*)d_in[o+10];
    mp.w1[s]  = (const float*)d_in[o+11];
    mp.bb1[s] = (const float*)d_in[o+12];
    mp.w2[s]  = (const float*)d_in[o+13];
    mp.bb2[s] = (const float*)d_in[o+14];
  }
  ap.att0 = xatt; ap.att1 = yatt;

  const bool use_mfma = (ws_size >= (size_t)2*73728*sizeof(_Float16));

  if (use_mfma)
    prep_kernel<<<147456/256, 256, 0, stream>>>(pp);   // independent of attn
  attn_kernel<<<NB_NWIN, 256, 0, stream>>>(ap);
  if (use_mfma)
    mlp_mfma_kernel<<<2*(TOKENS_TOTAL/MT), 256, 0, stream>>>(m2);
  else
    mlp_kernel<<<2*(TOKENS_TOTAL/MLP_TT), 256, 0, stream>>>(mp);
}

// Round 8
// 509.218 us; speedup vs baseline: 8.4555x; 3.8790x over previous
//
#include <hip/hip_runtime.h>
#include <hip/hip_fp16.h>
#include <math.h>

// Problem constants (Cross Swin block)
#define NB_B   8
#define NB_H   128
#define NB_W   128
#define NB_C   96
#define NB_WS  8
#define NB_SS  4
#define NB_NH  6
#define NB_HD  16
#define NB_N   64
#define NB_NWIN 2048
#define NB_L   (NB_H*NB_W)
#define NB_MLPH 384
#define TOKENS_TOTAL (NB_B*NB_L)   // 131072

typedef _Float16 half8 __attribute__((ext_vector_type(8)));
typedef float    f32x4 __attribute__((ext_vector_type(4)));

#define MLP_PACK_PER_STREAM 73728
#define ATT_PACK_PER_STREAM 36864
#define MLP_PACK_TOTAL (2*MLP_PACK_PER_STREAM)   // 147456 halves
#define ATT_PACK_TOTAL (2*ATT_PACK_PER_STREAM)   // 73728 halves
#define PACK_TOTAL (MLP_PACK_TOTAL + ATT_PACK_TOTAL)  // 221184
#define WS_NEED ((size_t)PACK_TOTAL*2)

// ==================== ATTENTION v2 (MFMA, S^T formulation) =================
// One LDS pool; regions single-stride, single-purpose over their lifetime.
//   PX [0,6144)       Xs  64x96  LN'd x
//   PY [6144,12288)   Ys  64x96  LN'd y
//   PK [12288,18432)  Ks  64x96  K row-major
//   PVt[18432,25344)  Vt  96x72  V transposed [dim][key]
//   PQ [25344,31992)  Qb  64x104 Q bounce (dies after qf8 loads + barrier)
//   PP [25344,29952)  Pb  64x72  P row-major  (wave-private rows)
//   PO [30016,32576)  Ob  64x40  O pair buffer (wave-private rows)
#define PX  0
#define PY  6144
#define PK  12288
#define PVt 18432
#define PQ  25344
#define PP  25344
#define PO  30016
#define POOL_HALVES 32576

struct AttnParams {
  const float* x;
  const float* y;
  const float* g1[2];
  const float* b1[2];
  const float* qb[2];
  const float* kvb[2];
  const float* pb[2];
  const float* rpb[2];
  const _Float16* wpack;   // [2][36864]: qwp|kwp|vwp|pwp (9216 each)
  float* att0;
  float* att1;
};

__global__ __launch_bounds__(256,2) void attn_mfma2_kernel(AttnParams P){
  __shared__ _Float16 POOL[POOL_HALVES];   // 65152 B
  __shared__ int lab[NB_N];                // +256 B = 65408 <= 65536

  const int tid  = threadIdx.x;
  const int w    = tid >> 6;       // wave id = query tile
  const int lane = tid & 63;
  const int mrow = lane & 15;
  const int quad = lane >> 4;
  const int win  = blockIdx.x;
  const int b    = win >> 8;
  const int widx = win & 255;
  const int wh   = widx >> 4;
  const int ww   = widx & 15;

  // Shift-mask labels (rolled-frame coordinates)
  if (tid < NB_N){
    int r = tid >> 3, c = tid & 7;
    int i = wh*NB_WS + r, j = ww*NB_WS + c;
    int ri = (i < NB_H-NB_WS) ? 0 : ((i < NB_H-NB_SS) ? 1 : 2);
    int rj = (j < NB_W-NB_WS) ? 0 : ((j < NB_W-NB_SS) ? 1 : 2);
    lab[tid] = ri*3 + rj;
  }

  // Load windows (roll folded into gather), stride 96
  for (int f = tid; f < NB_N*24; f += 256){
    int t  = f / 24;
    int q4 = f - t*24;
    int r = t >> 3, cc = t & 7;
    int i = wh*NB_WS + r, j = ww*NB_WS + cc;
    int oi = (i + NB_SS) & (NB_H-1), oj = (j + NB_SS) & (NB_W-1);
    size_t base = ((size_t)((b*NB_H + oi)*NB_W + oj))*NB_C + q4*4;
    float4 ux = *(const float4*)(P.x + base);
    float4 uy = *(const float4*)(P.y + base);
    int o = t*96 + q4*4;
    POOL[PX+o+0] = (_Float16)ux.x; POOL[PX+o+1] = (_Float16)ux.y;
    POOL[PX+o+2] = (_Float16)ux.z; POOL[PX+o+3] = (_Float16)ux.w;
    POOL[PY+o+0] = (_Float16)uy.x; POOL[PY+o+1] = (_Float16)uy.y;
    POOL[PY+o+2] = (_Float16)uy.z; POOL[PY+o+3] = (_Float16)uy.w;
  }
  __syncthreads();

  // LayerNorm in place (4 threads/row)
  {
    int t = tid >> 2, s = tid & 3;
    {
      float pm = 0.f;
      #pragma unroll
      for (int m=0;m<24;++m) pm += (float)POOL[PX + t*96 + s + 4*m];
      pm += __shfl_xor(pm,1); pm += __shfl_xor(pm,2);
      float mu = pm*(1.f/96.f);
      float pv = 0.f;
      #pragma unroll
      for (int m=0;m<24;++m){ float d = (float)POOL[PX + t*96+s+4*m]-mu; pv += d*d; }
      pv += __shfl_xor(pv,1); pv += __shfl_xor(pv,2);
      float rstd = rsqrtf(pv*(1.f/96.f) + 1e-5f);
      #pragma unroll
      for (int m=0;m<24;++m){
        int c = s + 4*m;
        POOL[PX + t*96+c] = (_Float16)(((float)POOL[PX + t*96+c]-mu)*rstd*P.g1[0][c] + P.b1[0][c]);
      }
    }
    {
      float pm = 0.f;
      #pragma unroll
      for (int m=0;m<24;++m) pm += (float)POOL[PY + t*96 + s + 4*m];
      pm += __shfl_xor(pm,1); pm += __shfl_xor(pm,2);
      float mu = pm*(1.f/96.f);
      float pv = 0.f;
      #pragma unroll
      for (int m=0;m<24;++m){ float d = (float)POOL[PY + t*96+s+4*m]-mu; pv += d*d; }
      pv += __shfl_xor(pv,1); pv += __shfl_xor(pv,2);
      float rstd = rsqrtf(pv*(1.f/96.f) + 1e-5f);
      #pragma unroll
      for (int m=0;m<24;++m){
        int c = s + 4*m;
        POOL[PY + t*96+c] = (_Float16)(((float)POOL[PY + t*96+c]-mu)*rstd*P.g1[1][c] + P.b1[1][c]);
      }
    }
  }
  __syncthreads();

  // Per-lane score tables. NEW mapping (S^T): query q = 16w+mrow (fixed per
  // lane); key = 16kt + quad*4 + r.
  int rpi6[4][4];
  float maddv[4][4];
  {
    int q  = w*16 + mrow;
    int lq = lab[q];
    int qr = q >> 3, qc = q & 7;
    #pragma unroll
    for (int kt=0;kt<4;++kt){
      #pragma unroll
      for (int r=0;r<4;++r){
        int key = kt*16 + quad*4 + r;
        int kr = key>>3, kc = key&7;
        rpi6[kt][r] = ((qr - kr + 7)*15 + (qc - kc + 7))*6;
        maddv[kt][r] = (lq == lab[key]) ? 0.f : -100.f;
      }
    }
  }

  const half8 z8 = {(_Float16)0,(_Float16)0,(_Float16)0,(_Float16)0,
                    (_Float16)0,(_Float16)0,(_Float16)0,(_Float16)0};

  for (int s2 = 0; s2 < 2; ++s2){
    const _Float16* qsrc = POOL + (s2 ? PY : PX);
    const _Float16* ksrc = POOL + (s2 ? PX : PY);
    const _Float16* wp   = P.wpack + s2*ATT_PACK_PER_STREAM;
    const _Float16* qwp  = wp;
    const _Float16* kwp  = wp + 9216;
    const _Float16* vwp  = wp + 18432;
    const _Float16* pwp  = wp + 27648;
    const float* qb  = P.qb[s2];
    const float* kvb = P.kvb[s2];
    const float* pb  = P.pb[s2];
    const float* rpbG= P.rpb[s2];

    // ---- Q GEMM -> Q bounce (stride 104), wave-private rows
    {
      half8 aq[3];
      #pragma unroll
      for (int kb=0;kb<3;++kb)
        aq[kb] = *(const half8*)(qsrc + (w*16+mrow)*96 + kb*32 + quad*8);
      #pragma unroll
      for (int nt=0;nt<6;++nt){
        f32x4 acc = {0.f,0.f,0.f,0.f};
        #pragma unroll
        for (int kb=0;kb<3;++kb){
          half8 bf = *(const half8*)(qwp + (((nt*3+kb)*64 + lane)<<3));
          acc = __builtin_amdgcn_mfma_f32_16x16x32_f16(aq[kb], bf, acc, 0,0,0);
        }
        int col = nt*16 + mrow;
        float bias = 0.25f*qb[col];
        #pragma unroll
        for (int r=0;r<4;++r)
          POOL[PQ + (w*16 + quad*4 + r)*104 + col] = (_Float16)(acc[r] + bias);
      }
    }
    // Q B-frags (own rows; same-wave RAW, waitcnt ordered by compiler)
    half8 qf8[3];
    #pragma unroll
    for (int hp=0;hp<3;++hp)
      qf8[hp] = *(const half8*)(POOL + PQ + (w*16+mrow)*104 + hp*32 + quad*8);

    // ---- K GEMM -> Ks (stride 96)
    {
      half8 ak[3];
      #pragma unroll
      for (int kb=0;kb<3;++kb)
        ak[kb] = *(const half8*)(ksrc + (w*16+mrow)*96 + kb*32 + quad*8);
      #pragma unroll
      for (int nt=0;nt<6;++nt){
        f32x4 acc = {0.f,0.f,0.f,0.f};
        #pragma unroll
        for (int kb=0;kb<3;++kb){
          half8 bf = *(const half8*)(kwp + (((nt*3+kb)*64 + lane)<<3));
          acc = __builtin_amdgcn_mfma_f32_16x16x32_f16(ak[kb], bf, acc, 0,0,0);
        }
        int col = nt*16 + mrow;
        float bias = kvb[col];
        #pragma unroll
        for (int r=0;r<4;++r)
          POOL[PK + (w*16 + quad*4 + r)*96 + col] = (_Float16)(acc[r] + bias);
      }
      // ---- V GEMM -> Vt[dim][key] (stride 72), wave-private key columns
      #pragma unroll
      for (int nt=0;nt<6;++nt){
        f32x4 acc = {0.f,0.f,0.f,0.f};
        #pragma unroll
        for (int kb=0;kb<3;++kb){
          half8 bf = *(const half8*)(vwp + (((nt*3+kb)*64 + lane)<<3));
          acc = __builtin_amdgcn_mfma_f32_16x16x32_f16(ak[kb], bf, acc, 0,0,0);
        }
        int col = nt*16 + mrow;          // dim
        float bias = kvb[96+col];
        #pragma unroll
        for (int r=0;r<4;++r)
          POOL[PVt + (nt*16+mrow)*72 + w*16 + quad*4 + r] = (_Float16)(acc[r] + bias);
      }
    }
    __syncthreads();   // publish Ks/Vt; Q region dead -> P/O may reuse it

    // ---- head loop: NO barriers inside (wave-private P/O, read-only K/Vt)
    f32x4 pracc[6];
    #pragma unroll
    for (int nt=0;nt<6;++nt) pracc[nt] = (f32x4){0.f,0.f,0.f,0.f};

    #pragma unroll
    for (int hp=0;hp<3;++hp){
      half8 kld[4];
      #pragma unroll
      for (int kt=0;kt<4;++kt)
        kld[kt] = *(const half8*)(POOL + PK + (kt*16+mrow)*96 + hp*32 + quad*8);

      #pragma unroll
      for (int sub=0;sub<2;++sub){
        const int h = hp*2 + sub;
        // S^T = K·Q^T over the pair's 32 dims, A(K) masked to this head's 16
        f32x4 sacc[4];
        #pragma unroll
        for (int kt=0;kt<4;++kt){
          half8 a8 = (sub == 0) ? ((quad < 2) ? kld[kt] : z8)
                                : ((quad >= 2) ? kld[kt] : z8);
          f32x4 z = {0.f,0.f,0.f,0.f};
          sacc[kt] = __builtin_amdgcn_mfma_f32_16x16x32_f16(a8, qf8[hp], z, 0,0,0);
        }
        // bias + mask; then softmax (all 16 values = one query per lane)
        float mx = -1e30f;
        #pragma unroll
        for (int kt=0;kt<4;++kt)
          #pragma unroll
          for (int r=0;r<4;++r){
            sacc[kt][r] += rpbG[rpi6[kt][r] + h] + maddv[kt][r];
            mx = fmaxf(mx, sacc[kt][r]);
          }
        mx = fmaxf(mx, __shfl_xor(mx,16));
        mx = fmaxf(mx, __shfl_xor(mx,32));
        float sm = 0.f;
        #pragma unroll
        for (int kt=0;kt<4;++kt)
          #pragma unroll
          for (int r=0;r<4;++r){
            float e = __expf(sacc[kt][r] - mx);
            sacc[kt][r] = e; sm += e;
          }
        sm += __shfl_xor(sm,16);
        sm += __shfl_xor(sm,32);
        float inv = 1.f/sm;
        // P row-major [query][key] (wave-private rows)
        #pragma unroll
        for (int kt=0;kt<4;++kt)
          #pragma unroll
          for (int r=0;r<4;++r)
            POOL[PP + (w*16+mrow)*72 + kt*16 + quad*4 + r] = (_Float16)(sacc[kt][r]*inv);

        // PV: O = P @ V_h  (A = P own rows, B = Vt shared read-only)
        f32x4 oacc = {0.f,0.f,0.f,0.f};
        #pragma unroll
        for (int kb=0;kb<2;++kb){
          half8 pa = *(const half8*)(POOL + PP + (w*16+mrow)*72 + kb*32 + quad*8);
          half8 vf = *(const half8*)(POOL + PVt + (h*16+mrow)*72 + kb*32 + quad*8);
          oacc = __builtin_amdgcn_mfma_f32_16x16x32_f16(pa, vf, oacc, 0,0,0);
        }
        // O pair buffer (wave-private rows): row = query, col = sub*16+dim
        #pragma unroll
        for (int r=0;r<4;++r)
          POOL[PO + (w*16 + quad*4 + r)*40 + sub*16 + mrow] = (_Float16)oacc[r];
      }
      // pair projection: A = O pair (own rows), B = packed proj frags
      half8 oa8 = *(const half8*)(POOL + PO + (w*16+mrow)*40 + quad*8);
      #pragma unroll
      for (int nt=0;nt<6;++nt){
        half8 bf = *(const half8*)(pwp + (((hp*6+nt)*64 + lane)<<3));
        pracc[nt] = __builtin_amdgcn_mfma_f32_16x16x32_f16(oa8, bf, pracc[nt], 0,0,0);
      }
    }

    // ---- epilogue: +pb +residual, store fp32 at un-rolled coords
    const float* resid = s2 ? P.y : P.x;
    float* outp = s2 ? P.att1 : P.att0;
    #pragma unroll
    for (int nt=0;nt<6;++nt){
      int col = nt*16 + mrow;
      float pbias = pb[col];
      #pragma unroll
      for (int r=0;r<4;++r){
        int t = w*16 + quad*4 + r;
        int rr = t>>3, cc = t&7;
        int i = wh*NB_WS + rr, j = ww*NB_WS + cc;
        int oi = (i + NB_SS) & (NB_H-1), oj = (j + NB_SS) & (NB_W-1);
        size_t g = ((size_t)((b*NB_H + oi)*NB_W + oj))*NB_C + col;
        outp[g] = pracc[nt][r] + pbias + resid[g];
      }
    }
    __syncthreads();   // protect Ks/Vt/Q-region before next stream
  }
}

// ==================== Unified prep: MLP + attention packing ================
// dst layout (halves): [2][73728] mlp (w1pack|w2pack), then [2][36864] attn
// (qwp|kwp|vwp|pwp). B-frag mapping: n = lane&15, k = (lane>>4)*8 + j.

struct PrepAllParams {
  const float* w1[2];
  const float* w2[2];
  const float* qw[2];
  const float* kvw[2];
  const float* pw[2];
  _Float16* dst;
};

__global__ __launch_bounds__(256) void prep_all_kernel(PrepAllParams P){
  int idx = blockIdx.x*256 + threadIdx.x;      // [0, 221184)
  float v;
  if (idx < MLP_PACK_TOTAL){
    int s2 = idx / 73728;
    int r  = idx - s2*73728;
    int which = r / 36864;
    int p  = r - which*36864;
    int j    = p & 7;
    int lane = (p >> 3) & 63;
    int frag = p >> 9;
    int k, n;
    if (which == 0){
      int kb = frag % 3, nt = frag / 3;
      k = kb*32 + (lane>>4)*8 + j;
      n = nt*16 + (lane & 15);
      v = P.w1[s2][k*NB_MLPH + n];
    } else {
      int kb = frag % 12, nt = frag / 12;
      k = kb*32 + (lane>>4)*8 + j;
      n = nt*16 + (lane & 15);
      v = P.w2[s2][k*NB_C + n];
    }
  } else {
    int q  = idx - MLP_PACK_TOTAL;             // < 73728
    int s2 = q / ATT_PACK_PER_STREAM;
    int p  = q - s2*ATT_PACK_PER_STREAM;
    int which = p / 9216;
    int r = p - which*9216;
    int j    = r & 7;
    int lane = (r>>3)&63;
    int frag = r>>9;
    if (which < 3){
      int kb = frag % 3, nt = frag / 3;
      int k = kb*32 + (lane>>4)*8 + j;
      int n = nt*16 + (lane&15);
      if (which == 0)      v = 0.25f * P.qw[s2][k*NB_C + n];
      else if (which == 1) v = P.kvw[s2][k*2*NB_C + n];
      else                 v = P.kvw[s2][k*2*NB_C + NB_C + n];
    } else {
      int nt = frag % 6, hp = frag / 6;
      int k = hp*32 + (lane>>4)*8 + j;
      int n = nt*16 + (lane&15);
      v = P.pw[s2][k*NB_C + n];
    }
  }
  P.dst[idx] = (_Float16)v;
}

// ==================== MLP (MFMA, proven) ===================================

#define MT 64
#define XS2 104
#define HS2 392

struct Mlp2Params {
  const float* g2[2];
  const float* bt2[2];
  const float* bb1[2];
  const float* bb2[2];
  const _Float16* wpack;
  float* out;
};

__global__ __launch_bounds__(256,2) void mlp_mfma_kernel(Mlp2Params P){
  __shared__ _Float16 Xs[MT*XS2];
  __shared__ _Float16 Hb[MT*HS2];
  float* Ftmp = (float*)Hb;

  const int tid  = threadIdx.x;
  const int wave = tid >> 6;
  const int lane = tid & 63;
  const int mrow = lane & 15;
  const int quad = lane >> 4;
  const int s2   = blockIdx.x >> 11;
  const int blk  = blockIdx.x & 2047;
  const int tok0 = blk * MT;

  float* outp = P.out + (size_t)s2*TOKENS_TOTAL*NB_C;
  const float* src = outp;

  for (int f = tid; f < MT*24; f += 256){
    int t = f / 24, q = f - t*24;
    float4 v = *(const float4*)(src + (size_t)(tok0+t)*NB_C + q*4);
    Ftmp[t*100+q*4+0] = v.x;
    Ftmp[t*100+q*4+1] = v.y;
    Ftmp[t*100+q*4+2] = v.z;
    Ftmp[t*100+q*4+3] = v.w;
  }
  __syncthreads();

  {
    int t = tid >> 2, s = tid & 3;
    float pm = 0.f;
    #pragma unroll
    for (int m=0;m<24;++m) pm += Ftmp[t*100 + s + 4*m];
    pm += __shfl_xor(pm,1); pm += __shfl_xor(pm,2);
    float mu = pm*(1.f/96.f);
    float pv = 0.f;
    #pragma unroll
    for (int m=0;m<24;++m){ float d = Ftmp[t*100+s+4*m]-mu; pv += d*d; }
    pv += __shfl_xor(pv,1); pv += __shfl_xor(pv,2);
    float rstd = rsqrtf(pv*(1.f/96.f) + 1e-5f);
    const float* g  = P.g2[s2];
    const float* bb = P.bt2[s2];
    #pragma unroll
    for (int m=0;m<24;++m){
      int c = s + 4*m;
      Xs[t*XS2+c] = (_Float16)((Ftmp[t*100+c]-mu)*rstd*g[c] + bb[c]);
    }
  }
  __syncthreads();

  const _Float16* w1p = P.wpack + (size_t)s2*73728;
  const _Float16* w2p = w1p + 36864;
  const float* b1 = P.bb1[s2];

  half8 Bf[18];
  #pragma unroll
  for (int nt=0; nt<6; ++nt)
    #pragma unroll
    for (int kb=0; kb<3; ++kb)
      Bf[nt*3+kb] = *(const half8*)(w1p + ((((wave*6+nt)*3 + kb)*64 + lane) << 3));

  #pragma unroll
  for (int rg=0; rg<4; ++rg){
    half8 Af[3];
    #pragma unroll
    for (int kb=0; kb<3; ++kb)
      Af[kb] = *(const half8*)(&Xs[(rg*16+mrow)*XS2 + kb*32 + quad*8]);
    #pragma unroll
    for (int nt=0; nt<6; ++nt){
      f32x4 acc = {0.f,0.f,0.f,0.f};
      #pragma unroll
      for (int kb=0; kb<3; ++kb)
        acc = __builtin_amdgcn_mfma_f32_16x16x32_f16(Af[kb], Bf[nt*3+kb], acc, 0, 0, 0);
      int gcol = wave*96 + nt*16 + mrow;
      float bias = b1[gcol];
      #pragma unroll
      for (int r=0;r<4;++r){
        float a = acc[r] + bias;
        a = 0.5f*a*(1.f + erff(a*0.70710678118654752f));
        Hb[(rg*16 + quad*4 + r)*HS2 + gcol] = (_Float16)a;
      }
    }
  }
  __syncthreads();

  const float* b2 = P.bb2[s2];
  half8 Ag[12];
  #pragma unroll
  for (int kb=0; kb<12; ++kb)
    Ag[kb] = *(const half8*)(&Hb[(wave*16+mrow)*HS2 + kb*32 + quad*8]);

  #pragma unroll
  for (int nt=0; nt<6; ++nt){
    f32x4 acc = {0.f,0.f,0.f,0.f};
    #pragma unroll
    for (int kb=0; kb<12; ++kb){
      half8 bv = *(const half8*)(w2p + (((nt*12+kb)*64 + lane) << 3));
      acc = __builtin_amdgcn_mfma_f32_16x16x32_f16(Ag[kb], bv, acc, 0, 0, 0);
    }
    int gcol = nt*16 + mrow;
    float bias = b2[gcol];
    #pragma unroll
    for (int r=0;r<4;++r){
      int row = wave*16 + quad*4 + r;
      size_t g = (size_t)(tok0+row)*NB_C + gcol;
      outp[g] = acc[r] + bias + src[g];
    }
  }
}

// ==================== Scalar fallbacks (ws too small) ======================

struct AttnFbParams {
  const float* x; const float* y;
  const float* g1[2]; const float* b1[2];
  const float* qw[2]; const float* qb[2];
  const float* kvw[2]; const float* kvb[2];
  const float* pw[2]; const float* pb[2];
  const float* rpb[2];
  float* att0; float* att1;
};

#define XSTR 104
#define QSTR 17
#define SSTR 66

__global__ __launch_bounds__(256) void attn_kernel(AttnFbParams P){
  __shared__ __half xs[NB_N*XSTR];
  __shared__ __half ys[NB_N*XSTR];
  __shared__ float  qh[NB_N*QSTR];
  __shared__ float  kh[NB_N*QSTR];
  __shared__ float  vh[NB_N*QSTR];
  __shared__ float  Sm[NB_N*SSTR];
  __shared__ int    lab[NB_N];

  const int tid  = threadIdx.x;
  const int win  = blockIdx.x;
  const int b    = win >> 8;
  const int widx = win & 255;
  const int wh   = widx >> 4;
  const int ww   = widx & 15;

  if (tid < NB_N){
    int r = tid >> 3, c = tid & 7;
    int i = wh*NB_WS + r, j = ww*NB_WS + c;
    int ri = (i < NB_H-NB_WS) ? 0 : ((i < NB_H-NB_SS) ? 1 : 2);
    int rj = (j < NB_W-NB_WS) ? 0 : ((j < NB_W-NB_SS) ? 1 : 2);
    lab[tid] = ri*3 + rj;
  }
  for (int f = tid; f < NB_N*24; f += 256){
    int t  = f / 24;
    int q4 = f - t*24;
    int r = t >> 3, cc = t & 7;
    int i = wh*NB_WS + r, j = ww*NB_WS + cc;
    int oi = (i + NB_SS) & (NB_H-1), oj = (j + NB_SS) & (NB_W-1);
    size_t base = ((size_t)((b*NB_H + oi)*NB_W + oj))*NB_C + q4*4;
    float4 ux = *(const float4*)(P.x + base);
    float4 uy = *(const float4*)(P.y + base);
    int o = t*XSTR + q4*4;
    xs[o+0]=__float2half(ux.x); xs[o+1]=__float2half(ux.y);
    xs[o+2]=__float2half(ux.z); xs[o+3]=__float2half(ux.w);
    ys[o+0]=__float2half(uy.x); ys[o+1]=__float2half(uy.y);
    ys[o+2]=__float2half(uy.z); ys[o+3]=__float2half(uy.w);
  }
  __syncthreads();
  {
    int t = tid >> 2, s = tid & 3;
    {
      float pm = 0.f;
      for (int m=0;m<24;++m) pm += __half2float(xs[t*XSTR + s + 4*m]);
      pm += __shfl_xor(pm,1); pm += __shfl_xor(pm,2);
      float mu = pm*(1.f/96.f);
      float pv = 0.f;
      for (int m=0;m<24;++m){ float d = __half2float(xs[t*XSTR+s+4*m])-mu; pv += d*d; }
      pv += __shfl_xor(pv,1); pv += __shfl_xor(pv,2);
      float rstd = rsqrtf(pv*(1.f/96.f) + 1e-5f);
      for (int m=0;m<24;++m){
        int c = s + 4*m;
        xs[t*XSTR+c] = __float2half((__half2float(xs[t*XSTR+c])-mu)*rstd*P.g1[0][c] + P.b1[0][c]);
      }
    }
    {
      float pm = 0.f;
      for (int m=0;m<24;++m) pm += __half2float(ys[t*XSTR + s + 4*m]);
      pm += __shfl_xor(pm,1); pm += __shfl_xor(pm,2);
      float mu = pm*(1.f/96.f);
      float pv = 0.f;
      for (int m=0;m<24;++m){ float d = __half2float(ys[t*XSTR+s+4*m])-mu; pv += d*d; }
      pv += __shfl_xor(pv,1); pv += __shfl_xor(pv,2);
      float rstd = rsqrtf(pv*(1.f/96.f) + 1e-5f);
      for (int m=0;m<24;++m){
        int c = s + 4*m;
        ys[t*XSTR+c] = __float2half((__half2float(ys[t*XSTR+c])-mu)*rstd*P.g1[1][c] + P.b1[1][c]);
      }
    }
  }
  __syncthreads();

  for (int s2 = 0; s2 < 2; ++s2){
    const __half* qsrc = s2 ? ys : xs;
    const __half* ksrc = s2 ? xs : ys;
    const float* qw  = P.qw[s2];
    const float* qb  = P.qb[s2];
    const float* kvw = P.kvw[s2];
    const float* kvb = P.kvb[s2];
    const float* pw  = P.pw[s2];
    const float* pb  = P.pb[s2];
    const float* rpb = P.rpb[s2];

    float accO[24];
    for (int m=0;m<24;++m) accO[m] = 0.f;

    for (int h = 0; h < NB_NH; ++h){
      for (int f = tid; f < NB_N*NB_HD; f += 256){
        int d = f & 15, t = f >> 4;
        int c = h*16 + d;
        float aq = 0.f, ak = 0.f, av = 0.f;
        for (int k = 0; k < 96; ++k){
          float xv = __half2float(qsrc[t*XSTR+k]);
          float yv = __half2float(ksrc[t*XSTR+k]);
          aq += xv * qw [k*96  + c];
          ak += yv * kvw[k*192 + c];
          av += yv * kvw[k*192 + 96 + c];
        }
        qh[t*QSTR+d] = (aq + qb[c]) * 0.25f;
        kh[t*QSTR+d] = ak + kvb[c];
        vh[t*QSTR+d] = av + kvb[96+c];
      }
      __syncthreads();
      for (int f = tid; f < NB_N*NB_N; f += 256){
        int j = f & 63, i = f >> 6;
        float a = 0.f;
        for (int d=0; d<16; ++d) a += qh[i*QSTR+d]*kh[j*QSTR+d];
        int iq = i>>3, jq = i&7, ik = j>>3, jk = j&7;
        int rp = (iq-ik+7)*15 + (jq-jk+7);
        a += rpb[rp*NB_NH + h];
        a += (lab[i]==lab[j]) ? 0.f : -100.f;
        Sm[i*SSTR + j] = a;
      }
      __syncthreads();
      {
        int t = tid >> 2, s = tid & 3;
        float mx = -1e30f;
        for (int m=0;m<16;++m) mx = fmaxf(mx, Sm[t*SSTR + s + 4*m]);
        mx = fmaxf(mx, __shfl_xor(mx,1)); mx = fmaxf(mx, __shfl_xor(mx,2));
        float ev[16]; float sm = 0.f;
        for (int m=0;m<16;++m){ ev[m] = __expf(Sm[t*SSTR+s+4*m]-mx); sm += ev[m]; }
        sm += __shfl_xor(sm,1); sm += __shfl_xor(sm,2);
        float inv = 1.f/sm;
        for (int m=0;m<16;++m) Sm[t*SSTR+s+4*m] = ev[m]*inv;
      }
      __syncthreads();
      for (int f = tid; f < NB_N*NB_HD; f += 256){
        int d = f & 15, i = f >> 4;
        float a = 0.f;
        for (int j=0;j<64;++j) a += Sm[i*SSTR+j]*vh[j*QSTR+d];
        qh[i*QSTR+d] = a;
      }
      __syncthreads();
      for (int m=0;m<24;++m){
        int f = tid + 256*m;
        int c = f % 96, t = f / 96;
        float a = accO[m];
        for (int k=0;k<16;++k) a += qh[t*QSTR+k]*pw[(h*16+k)*96 + c];
        accO[m] = a;
      }
      __syncthreads();
    }
    const float* resid = s2 ? P.y : P.x;
    float* outp = s2 ? P.att1 : P.att0;
    for (int m=0;m<24;++m){
      int f = tid + 256*m;
      int c = f % 96, t = f / 96;
      int r = t>>3, cc = t&7;
      int i = wh*NB_WS + r, j = ww*NB_WS + cc;
      int oi = (i + NB_SS) & (NB_H-1), oj = (j + NB_SS) & (NB_W-1);
      size_t g = ((size_t)((b*NB_H + oi)*NB_W + oj))*NB_C + c;
      outp[g] = accO[m] + pb[c] + resid[g];
    }
    __syncthreads();
  }
}

struct MlpParams {
  const float* src0;
  const float* src1;
  const float* g2[2];
  const float* bt2[2];
  const float* w1[2];
  const float* bb1[2];
  const float* w2[2];
  const float* bb2[2];
  float* out;
};

#define MLP_TT 16

__global__ __launch_bounds__(256) void mlp_kernel(MlpParams P){
  __shared__ float xt[MLP_TT*100];
  __shared__ float hh[MLP_TT*388];

  const int tid  = threadIdx.x;
  const int s2   = blockIdx.x >> 13;
  const int blk  = blockIdx.x & 8191;
  const int tok0 = blk * MLP_TT;
  const float* src = s2 ? P.src1 : P.src0;

  for (int f = tid; f < MLP_TT*96; f += 256){
    int t = f / 96, c = f - t*96;
    xt[t*100+c] = src[(size_t)(tok0+t)*96 + c];
  }
  __syncthreads();
  {
    int t = tid >> 4, s = tid & 15;
    float pm = 0.f;
    for (int m=0;m<6;++m) pm += xt[t*100 + s + 16*m];
    pm += __shfl_xor(pm,1); pm += __shfl_xor(pm,2);
    pm += __shfl_xor(pm,4); pm += __shfl_xor(pm,8);
    float mu = pm*(1.f/96.f);
    float pv = 0.f;
    for (int m=0;m<6;++m){ float d = xt[t*100+s+16*m]-mu; pv += d*d; }
    pv += __shfl_xor(pv,1); pv += __shfl_xor(pv,2);
    pv += __shfl_xor(pv,4); pv += __shfl_xor(pv,8);
    float rstd = rsqrtf(pv*(1.f/96.f) + 1e-5f);
    const float* g = P.g2[s2];
    const float* bb = P.bt2[s2];
    for (int m=0;m<6;++m){
      int c = s+16*m;
      xt[t*100+c] = (xt[t*100+c]-mu)*rstd*g[c] + bb[c];
    }
  }
  __syncthreads();
  {
    const float* w1 = P.w1[s2];
    const float* b1 = P.bb1[s2];
    for (int f = tid; f < MLP_TT*NB_MLPH; f += 256){
      int t = f / NB_MLPH, j = f - t*NB_MLPH;
      float a = 0.f;
      for (int k=0;k<96;++k) a += xt[t*100+k]*w1[k*NB_MLPH+j];
      a += b1[j];
      hh[t*388+j] = 0.5f*a*(1.f + erff(a*0.70710678118654752f));
    }
  }
  __syncthreads();
  {
    const float* w2 = P.w2[s2];
    const float* b2v = P.bb2[s2];
    float* outp = P.out + (size_t)s2*TOKENS_TOTAL*96;
    for (int f = tid; f < MLP_TT*96; f += 256){
      int t = f / 96, c = f - t*96;
      float a = 0.f;
      for (int j=0;j<NB_MLPH;++j) a += hh[t*388+j]*w2[j*96+c];
      size_t gidx = (size_t)(tok0+t)*96 + c;
      a += b2v[c] + src[gidx];
      outp[gidx] = a;
    }
  }
}

// ==================== launcher =============================================

extern "C" void kernel_launch(void* const* d_in, const int* in_sizes, int n_in,
                              void* d_out, int out_size, void* d_ws, size_t ws_size,
                              hipStream_t stream){
  float* xatt = (float*)d_out;
  float* yatt = xatt + (size_t)TOKENS_TOTAL*NB_C;

  _Float16* mlp_pack  = (_Float16*)d_ws;
  _Float16* attn_pack = mlp_pack + MLP_PACK_TOTAL;

  AttnParams ap;
  ap.x = (const float*)d_in[0];
  ap.y = (const float*)d_in[1];
  ap.wpack = attn_pack;
  ap.att0 = xatt; ap.att1 = yatt;

  AttnFbParams af;
  af.x = ap.x; af.y = ap.y; af.att0 = xatt; af.att1 = yatt;

  PrepAllParams pa;     pa.dst = mlp_pack;
  Mlp2Params m2;        m2.wpack = mlp_pack; m2.out = (float*)d_out;
  MlpParams mp;         mp.src0 = xatt; mp.src1 = yatt; mp.out = (float*)d_out;

  for (int s=0;s<2;++s){
    int o = 4 + 15*s;
    ap.g1[s]  = (const float*)d_in[o+0];
    ap.b1[s]  = (const float*)d_in[o+1];
    ap.qb[s]  = (const float*)d_in[o+3];
    ap.kvb[s] = (const float*)d_in[o+5];
    ap.pb[s]  = (const float*)d_in[o+7];
    ap.rpb[s] = (const float*)d_in[o+8];

    pa.qw[s]  = (const float*)d_in[o+2];
    pa.kvw[s] = (const float*)d_in[o+4];
    pa.pw[s]  = (const float*)d_in[o+6];
    pa.w1[s]  = (const float*)d_in[o+11];
    pa.w2[s]  = (const float*)d_in[o+13];

    af.g1[s]  = (const float*)d_in[o+0];
    af.b1[s]  = (const float*)d_in[o+1];
    af.qw[s]  = (const float*)d_in[o+2];
    af.qb[s]  = (const float*)d_in[o+3];
    af.kvw[s] = (const float*)d_in[o+4];
    af.kvb[s] = (const float*)d_in[o+5];
    af.pw[s]  = (const float*)d_in[o+6];
    af.pb[s]  = (const float*)d_in[o+7];
    af.rpb[s] = (const float*)d_in[o+8];

    m2.g2[s]  = (const float*)d_in[o+9];
    m2.bt2[s] = (const float*)d_in[o+10];
    m2.bb1[s] = (const float*)d_in[o+12];
    m2.bb2[s] = (const float*)d_in[o+14];

    mp.g2[s]  = (const float*)d_in[o+9];
    mp.bt2[s] = (const float*)d_in[o+10];
    mp.w1[s]  = (const float*)d_in[o+11];
    mp.bb1[s] = (const float*)d_in[o+12];
    mp.w2[s]  = (const float*)d_in[o+13];
    mp.bb2[s] = (const float*)d_in[o+14];
  }

  const bool use_mfma = (ws_size >= WS_NEED);

  if (use_mfma){
    prep_all_kernel<<<PACK_TOTAL/256, 256, 0, stream>>>(pa);
    attn_mfma2_kernel<<<NB_NWIN, 256, 0, stream>>>(ap);
    mlp_mfma_kernel<<<2*(TOKENS_TOTAL/MT), 256, 0, stream>>>(m2);
  } else {
    attn_kernel<<<NB_NWIN, 256, 0, stream>>>(af);
    mlp_kernel<<<2*(TOKENS_TOTAL/MLP_TT), 256, 0, stream>>>(mp);
  }
}